// Round 1
// baseline (151.491 us; speedup 1.0000x reference)
//
#include <hip/hip_runtime.h>
#include <hip/hip_bf16.h>
#include <stdint.h>

typedef __attribute__((ext_vector_type(8))) short short8;
typedef __attribute__((ext_vector_type(16))) float f32x16;

namespace {
constexpr int NB = 4, NL = 2048, NH = 8, NE = 64, ND = 64;
constexpr int QBLK = 128;   // q rows per block (4 waves x 32)
constexpr int KVBLK = 32;   // kv tile
constexpr int NWAVE = 4;
}

__device__ __forceinline__ uint32_t bfbits(float x) {
  uint32_t u = __builtin_bit_cast(uint32_t, x);
  return (u + 0x7FFFu + ((u >> 16) & 1u)) >> 16;  // RNE f32->bf16
}
__device__ __forceinline__ uint32_t pkbf(float lo, float hi) {
  return bfbits(lo) | (bfbits(hi) << 16);
}

// S^T = K·Q^T via mfma(K,Q): lane holds q = lane&31, key(reg,hi) = (r&3)+8*(r>>2)+4*hi
// O^T = V^T·P^T: O acc column = lane&31 = q  -> rescale factor lane-local.
__global__ __launch_bounds__(256)
void sattn_fwd(const float* __restrict__ Qg, const float* __restrict__ Kg,
               const float* __restrict__ Vg, float* __restrict__ Og)
{
  const int bh   = blockIdx.x;                       // 0..31 ; id%8 = bh%8 -> XCD-pinned per (b,h)
  const int qblk = (NL / QBLK - 1) - blockIdx.y;     // longest blocks dispatch first
  const int b = bh >> 3;
  const int h = bh & 7;

  const int tid  = threadIdx.x;
  const int wave = tid >> 6;
  const int lane = tid & 63;
  const int ln31 = lane & 31;
  const int hi   = lane >> 5;

  __shared__ __align__(16) union {
    struct {
      ushort kt[KVBLK * 64];   // byte = key*128 + ((e*2) ^ ((key&7)<<4))
      ushort vt[64 * 40];      // byte = d*80  + ((k*2) ^ (((d>>3)&3)<<4)), rows padded to 80B
    } s;
    float ep[NWAVE * 32 * 68]; // epilogue transpose buffer, 272B rows (16B aligned)
  } lds;

  const int q0  = qblk * QBLK;
  const int q0w = q0 + wave * 32;
  const int qi  = q0w + ln31;           // this lane's q row (softmax + O column)

  // ---- Q fragments: B-operand of S^T mfma: col=q=lane&31, k(e) = st*16 + hi*8 + j ----
  short8 qf[4];
  {
    const float* qp = Qg + (((size_t)b * NL + qi) * NH + h) * NE;
    #pragma unroll
    for (int st = 0; st < 4; ++st) {
      const float* qpe = qp + st * 16 + hi * 8;
      union { short8 v; uint32_t u[4]; } f;
      #pragma unroll
      for (int j = 0; j < 4; ++j) f.u[j] = pkbf(qpe[2 * j], qpe[2 * j + 1]);
      qf[st] = f.v;
    }
  }

  f32x16 acc0, acc1;   // O^T accumulators: d-blocks [0..31], [32..63]; col q = lane&31
  #pragma unroll
  for (int i = 0; i < 16; ++i) { acc0[i] = 0.f; acc1[i] = 0.f; }
  float mrun = -1e30f;   // finite sentinel (never -inf: avoids NaN in corr)
  float lsum = 0.f;

  const int srow = tid >> 3;        // staging: key/value row 0..31
  const int scol = (tid & 7) * 8;   // staging: e/d chunk base

  const int NT = qblk * 4 + 4;
  const float SCALE = 0.125f;       // 1/sqrt(64)
  const float L2E = 1.44269504f;

  for (int t = 0; t < NT; ++t) {
    const int kv0 = t * KVBLK;
    __syncthreads();  // previous tile's LDS readers done before overwrite

    { // stage K tile (fp32 -> bf16, XOR-swizzled, one b128 store/thread)
      const float* kp = Kg + (((size_t)b * NL + kv0 + srow) * NH + h) * NE + scol;
      uint32_t w0 = pkbf(kp[0], kp[1]);
      uint32_t w1 = pkbf(kp[2], kp[3]);
      uint32_t w2 = pkbf(kp[4], kp[5]);
      uint32_t w3 = pkbf(kp[6], kp[7]);
      uint32_t* dst = (uint32_t*)((char*)lds.s.kt + srow * 128 +
                                  ((scol * 2) ^ ((srow & 7) << 4)));
      dst[0] = w0; dst[1] = w1; dst[2] = w2; dst[3] = w3;
    }
    { // stage V transposed: Vt[d][k], swizzled
      const float* vp = Vg + (((size_t)b * NL + kv0 + srow) * NH + h) * ND + scol;
      #pragma unroll
      for (int j = 0; j < 8; ++j) {
        int d = scol + j;
        *(ushort*)((char*)lds.s.vt + d * 80 +
                   ((srow * 2) ^ (((d >> 3) & 3) << 4))) = (ushort)bfbits(vp[j]);
      }
    }
    __syncthreads();

    if (kv0 > q0w + 31) continue;   // wave-uniform skip; barrier counts still match

    // ---- S^T = K · Q^T ----
    f32x16 s;
    #pragma unroll
    for (int i = 0; i < 16; ++i) s[i] = 0.f;
    #pragma unroll
    for (int st = 0; st < 4; ++st) {
      const short8 kf = *(const short8*)((const char*)lds.s.kt + ln31 * 128 +
                         (((st * 16 + hi * 8) * 2) ^ ((ln31 & 7) << 4)));
      s = __builtin_amdgcn_mfma_f32_32x32x16_bf16(kf, qf[st], s, 0, 0, 0);
    }

    // ---- masks + logits (strided mask zeroes logit; causal -> -inf) ----
    float tmax = -__builtin_inff();
    #pragma unroll
    for (int r = 0; r < 16; ++r) {
      int kj = kv0 + (r & 3) + 8 * (r >> 2) + 4 * hi;
      int diff = qi - kj;
      float lg;
      if (diff < 0)                                        lg = -__builtin_inff();
      else if (diff >= 2 && (diff & (diff - 1)) == 0)      lg = 0.0f;   // value-masked: logit exactly 0
      else                                                 lg = s[r] * SCALE;
      s[r] = lg;
      tmax = fmaxf(tmax, lg);
    }
    tmax = fmaxf(tmax, __shfl_xor(tmax, 32));   // partner holds other 16 keys of this q row
    float mnew = fmaxf(mrun, tmax);             // stays finite (sentinel)
    float corr = exp2f((mrun - mnew) * L2E);
    float ps = 0.f;
    #pragma unroll
    for (int r = 0; r < 16; ++r) {
      float pv = exp2f((s[r] - mnew) * L2E);    // -inf -> 0; logit<=mnew always
      ps += pv;
      s[r] = pv;
    }
    ps += __shfl_xor(ps, 32);
    lsum = lsum * corr + ps;
    mrun = mnew;
    #pragma unroll
    for (int i = 0; i < 16; ++i) { acc0[i] *= corr; acc1[i] *= corr; }

    // ---- pack P -> bf16 B-fragments (keys hi*8..+7 per 16-key step) ----
    uint32_t w[8], rw[8];
    #pragma unroll
    for (int pr2 = 0; pr2 < 8; ++pr2) w[pr2] = pkbf(s[2 * pr2], s[2 * pr2 + 1]);
    #pragma unroll
    for (int pr2 = 0; pr2 < 8; ++pr2) rw[pr2] = __shfl_xor(w[pr2], 32);
    union { short8 v; uint32_t u[4]; } f0, f1;
    if (hi == 0) {
      f0.u[0] = w[0];  f0.u[1] = w[1];  f0.u[2] = rw[0]; f0.u[3] = rw[1]; // keys 0..7
      f1.u[0] = w[4];  f1.u[1] = w[5];  f1.u[2] = rw[4]; f1.u[3] = rw[5]; // keys 16..23
    } else {
      f0.u[0] = rw[2]; f0.u[1] = rw[3]; f0.u[2] = w[2];  f0.u[3] = w[3];  // keys 8..15
      f1.u[0] = rw[6]; f1.u[1] = rw[7]; f1.u[2] = w[6];  f1.u[3] = w[7];  // keys 24..31
    }

    // ---- O^T += V^T · P^T ----
    {
      const char* base = (const char*)lds.s.vt;
      const int d0 = ln31,      sw0 = ((d0 >> 3) & 3) << 4;
      const int d1 = 32 + ln31, sw1 = ((d1 >> 3) & 3) << 4;
      short8 a00 = *(const short8*)(base + d0 * 80 + ((hi * 16) ^ sw0));       // keys 0..15
      short8 a01 = *(const short8*)(base + d0 * 80 + ((32 + hi * 16) ^ sw0));  // keys 16..31
      short8 a10 = *(const short8*)(base + d1 * 80 + ((hi * 16) ^ sw1));
      short8 a11 = *(const short8*)(base + d1 * 80 + ((32 + hi * 16) ^ sw1));
      acc0 = __builtin_amdgcn_mfma_f32_32x32x16_bf16(a00, f0.v, acc0, 0, 0, 0);
      acc0 = __builtin_amdgcn_mfma_f32_32x32x16_bf16(a01, f1.v, acc0, 0, 0, 0);
      acc1 = __builtin_amdgcn_mfma_f32_32x32x16_bf16(a10, f0.v, acc1, 0, 0, 0);
      acc1 = __builtin_amdgcn_mfma_f32_32x32x16_bf16(a11, f1.v, acc1, 0, 0, 0);
    }
  }

  // ---- epilogue: O^T regs -> LDS -> coalesced O stores ----
  __syncthreads();                      // last tile's LDS readers done; union repurposed
  const float inv = 1.0f / lsum;        // every row has its diagonal key -> lsum > 0
  float* ep = lds.ep + wave * (32 * 68);
  #pragma unroll
  for (int r = 0; r < 16; ++r) {
    int drow = (r & 3) + 8 * (r >> 2) + 4 * hi;
    ep[ln31 * 68 + drow]      = acc0[r] * inv;
    ep[ln31 * 68 + 32 + drow] = acc1[r] * inv;
  }
  __syncthreads();
  const float* epr = lds.ep + wave * (32 * 68);
  #pragma unroll
  for (int rep = 0; rep < 8; ++rep) {
    int q  = rep * 4 + (lane >> 4);     // 4 rows x 256B contiguous per instr
    int d4 = (lane & 15) * 4;
    float4 val = *(const float4*)(epr + q * 68 + d4);
    float* op = Og + (((size_t)b * NL + q0w + q) * NH + h) * ND + d4;
    *(float4*)op = val;
  }
}

extern "C" void kernel_launch(void* const* d_in, const int* in_sizes, int n_in,
                              void* d_out, int out_size, void* d_ws, size_t ws_size,
                              hipStream_t stream) {
  const float* Q = (const float*)d_in[0];
  const float* K = (const float*)d_in[1];
  const float* V = (const float*)d_in[2];
  float* O = (float*)d_out;
  dim3 grid(NB * NH, NL / QBLK);   // (32, 16); y reversed inside kernel
  sattn_fwd<<<grid, dim3(256), 0, stream>>>(Q, K, V, O);
}

// Round 2
// 83.251 us; speedup vs baseline: 1.8197x; 1.8197x over previous
//
#include <hip/hip_runtime.h>
#include <hip/hip_bf16.h>
#include <stdint.h>

typedef __attribute__((ext_vector_type(8))) short short8;
typedef __attribute__((ext_vector_type(16))) float f32x16;

namespace {
constexpr int NB = 4, NL = 2048, NH = 8, NE = 64, ND = 64;
constexpr int QBLK = 128;   // q rows per block (4 waves x 32)
constexpr int KVBLK = 32;   // kv tile
constexpr int NWAVE = 4;
constexpr float KS  = 0.125f * 1.44269504f;  // (1/sqrt(E)) * log2(e): exp2-domain logits
constexpr float THR = 11.5f;                 // defer-max threshold (~8 nats)
}

__device__ __forceinline__ ushort bfb(float x) {          // compiler emits v_cvt_pk fusions
  __hip_bfloat16 b(x);
  return __builtin_bit_cast(ushort, b);
}
__device__ __forceinline__ uint32_t pkbf(float lo, float hi) {
  return (uint32_t)bfb(lo) | ((uint32_t)bfb(hi) << 16);
}

// S^T = K·Q^T via mfma(K,Q): lane holds q = lane&31, key(reg,hi) = (r&3)+8*(r>>2)+4*hi
// O^T = V^T·P^T: O acc column = lane&31 = q  -> softmax state fully lane-local.
__global__ __launch_bounds__(256)
void sattn_fwd(const float* __restrict__ Qg, const float* __restrict__ Kg,
               const float* __restrict__ Vg, float* __restrict__ Og)
{
  const int bh = blockIdx.x;                 // linear%8 = bh%8 -> (b,h) pinned to one XCD
  const int y  = blockIdx.y;
  const int qblk = (y < 8) ? (15 - y) : (y - 8);  // blocks i and i+256 sum to 68 tile-units
  const int b = bh >> 3, h = bh & 7;

  const int tid  = threadIdx.x;
  const int wave = tid >> 6;
  const int lane = tid & 63;
  const int ln31 = lane & 31;
  const int hi   = lane >> 5;

  __shared__ __align__(16) union {
    struct {
      ushort kt[KVBLK * 64];   // byte = key*128 + ((e*2) ^ ((key&7)<<4))
      ushort vt[64 * 40];      // byte = d*80  + ((k*2) ^ (((d>>3)&3)<<4))
    } s;
    float ep[NWAVE * 32 * 68]; // epilogue transpose buffer
  } lds;

  const int q0w = qblk * QBLK + wave * 32;
  const int qi  = q0w + ln31;          // this lane's q row
  const int tw  = qblk * 4 + wave;     // wave's diagonal tile index
  const int NT  = qblk * 4 + 4;        // tiles the BLOCK must stage

  // ---- Q fragments (B-operand: col=q=lane&31, k(e)=st*16+hi*8+j) ----
  short8 qf[4];
  {
    const float* qp = Qg + (((size_t)b * NL + qi) * NH + h) * NE;
    #pragma unroll
    for (int st = 0; st < 4; ++st) {
      const float* qpe = qp + st * 16 + hi * 8;
      union { short8 v; uint32_t u[4]; } f;
      #pragma unroll
      for (int j = 0; j < 4; ++j) f.u[j] = pkbf(qpe[2 * j], qpe[2 * j + 1]);
      qf[st] = f.v;
    }
  }

  f32x16 acc0, acc1;
  #pragma unroll
  for (int i = 0; i < 16; ++i) { acc0[i] = 0.f; acc1[i] = 0.f; }
  float mrun = -1e30f, lsum = 0.f;

  // staging maps
  const int krow = tid >> 3,        kcol = (tid & 7) * 8;   // K: 1 row x 8 e
  const int vrow = (tid >> 4) * 2,  vcol = (tid & 15) * 4;  // V: 2 rows x 4 d
  const float* kpp = Kg + (((size_t)b * NL + krow) * NH + h) * NE + kcol;
  const float* vpp = Vg + (((size_t)b * NL + vrow) * NH + h) * ND + vcol;
  constexpr int KSTEP = KVBLK * NH * NE;   // floats per tile advance (K and V identical)

  // prefetch tile 0 into registers (T14: issue early, write late)
  float kx[8], vx[8];
  #pragma unroll
  for (int j = 0; j < 8; ++j) kx[j] = kpp[j];
  #pragma unroll
  for (int j = 0; j < 4; ++j) { vx[j] = vpp[j]; vx[4 + j] = vpp[j + NH * ND]; }

  for (int t = 0; t < NT; ++t) {
    const int kv0 = t * KVBLK;
    __syncthreads();   // readers of tile t-1 done
    { // write tile t from prefetched regs (cvt_pk fused by compiler)
      uint32_t* kd = (uint32_t*)((char*)lds.s.kt + krow * 128 +
                                 ((kcol * 2) ^ ((krow & 7) << 4)));
      kd[0] = pkbf(kx[0], kx[1]); kd[1] = pkbf(kx[2], kx[3]);
      kd[2] = pkbf(kx[4], kx[5]); kd[3] = pkbf(kx[6], kx[7]);
      #pragma unroll
      for (int j = 0; j < 4; ++j) {
        int d = vcol + j;
        *(uint32_t*)((char*)lds.s.vt + d * 80 +
                     ((vrow * 2) ^ (((d >> 3) & 3) << 4))) = pkbf(vx[j], vx[4 + j]);
      }
    }
    { // issue prefetch of tile t+1 (latency hides under compute below)
      int tn = (t + 1 < NT) ? t + 1 : t;
      const float* kp = kpp + (size_t)tn * KSTEP;
      const float* vp = vpp + (size_t)tn * KSTEP;
      #pragma unroll
      for (int j = 0; j < 8; ++j) kx[j] = kp[j];
      #pragma unroll
      for (int j = 0; j < 4; ++j) { vx[j] = vp[j]; vx[4 + j] = vp[j + NH * ND]; }
    }
    __syncthreads();   // tile t ready
    if (t > tw) continue;   // wave-uniform; barrier counts stay matched

    // ---- S^T = K · Q^T ----
    f32x16 s;
    #pragma unroll
    for (int i = 0; i < 16; ++i) s[i] = 0.f;
    const char* kb  = (const char*)lds.s.kt + ln31 * 128;
    const int   ksw = (ln31 & 7) << 4;
    __builtin_amdgcn_s_setprio(1);
    #pragma unroll
    for (int st = 0; st < 4; ++st) {
      short8 kf = *(const short8*)(kb + ((st * 32 + hi * 16) ^ ksw));
      s = __builtin_amdgcn_mfma_f32_32x32x16_bf16(kf, qf[st], s, 0, 0, 0);
    }
    __builtin_amdgcn_s_setprio(0);

    // ---- logits (exp2 domain) + masks; 3 wave-uniform tile flavors ----
    const int delta = q0w - kv0;
    const int qrelh = (qi - kv0) - 4 * hi;   // diff = qrelh - cr
    float tmax = -__builtin_inff();
    if (t == tw) {            // diagonal: causal + full pow2 check
      #pragma unroll
      for (int r = 0; r < 16; ++r) {
        const int cr = (r & 3) + 8 * (r >> 2);
        int diff = qrelh - cr;
        float lg = s[r] * KS;
        bool p2 = (diff > 1) & ((diff & (diff - 1)) == 0);
        lg = p2 ? 0.f : lg;
        lg = (diff < 0) ? -__builtin_inff() : lg;
        s[r] = lg; tmax = fmaxf(tmax, lg);
      }
    } else {
      int pmax = 1 << (31 - __clz(delta + 31));   // largest pow2 <= max diff in tile
      if (pmax >= delta - 31) {   // some lane/key hits a pow2 stride
        #pragma unroll
        for (int r = 0; r < 16; ++r) {
          const int cr = (r & 3) + 8 * (r >> 2);
          int diff = qrelh - cr;
          float lg = s[r] * KS;
          bool p2 = (diff > 1) & ((diff & (diff - 1)) == 0);
          s[r] = lg = p2 ? 0.f : lg;
          tmax = fmaxf(tmax, lg);
        }
      } else {                    // clean: no mask at all
        #pragma unroll
        for (int r = 0; r < 16; ++r) {
          float lg = s[r] * KS;
          s[r] = lg; tmax = fmaxf(tmax, lg);
        }
      }
    }

    // ---- online softmax, defer-max (T13) ----
    tmax = fmaxf(tmax, __shfl_xor(tmax, 32));
    if (!__all(tmax <= mrun + THR)) {
      float mnew = fmaxf(mrun, tmax);
      float corr = exp2f(mrun - mnew);
      mrun = mnew; lsum *= corr;
      #pragma unroll
      for (int i = 0; i < 16; ++i) { acc0[i] *= corr; acc1[i] *= corr; }
    }
    float ps0 = 0, ps1 = 0, ps2 = 0, ps3 = 0;
    #pragma unroll
    for (int r = 0; r < 16; r += 4) {
      float p0 = exp2f(s[r] - mrun),     p1 = exp2f(s[r + 1] - mrun);
      float p2 = exp2f(s[r + 2] - mrun), p3 = exp2f(s[r + 3] - mrun);
      s[r] = p0; s[r + 1] = p1; s[r + 2] = p2; s[r + 3] = p3;
      ps0 += p0; ps1 += p1; ps2 += p2; ps3 += p3;
    }
    float ps = (ps0 + ps1) + (ps2 + ps3);
    ps += __shfl_xor(ps, 32);
    lsum += ps;

    // ---- pack P -> bf16 fragments (4 shfls via pre-select) ----
    uint32_t w0 = pkbf(s[0],  s[1]),  w1 = pkbf(s[2],  s[3]);
    uint32_t w2 = pkbf(s[4],  s[5]),  w3 = pkbf(s[6],  s[7]);
    uint32_t w4 = pkbf(s[8],  s[9]),  w5 = pkbf(s[10], s[11]);
    uint32_t w6 = pkbf(s[12], s[13]), w7 = pkbf(s[14], s[15]);
    uint32_t y0 = __shfl_xor(hi ? w0 : w2, 32);
    uint32_t y1 = __shfl_xor(hi ? w1 : w3, 32);
    uint32_t y2 = __shfl_xor(hi ? w4 : w6, 32);
    uint32_t y3 = __shfl_xor(hi ? w5 : w7, 32);
    union { short8 v; uint32_t u[4]; } f0, f1;
    if (hi == 0) {
      f0.u[0] = w0; f0.u[1] = w1; f0.u[2] = y0; f0.u[3] = y1;   // keys 0..15
      f1.u[0] = w4; f1.u[1] = w5; f1.u[2] = y2; f1.u[3] = y3;   // keys 16..31
    } else {
      f0.u[0] = y0; f0.u[1] = y1; f0.u[2] = w2; f0.u[3] = w3;
      f1.u[0] = y2; f1.u[1] = y3; f1.u[2] = w6; f1.u[3] = w7;
    }

    // ---- O^T += V^T · P^T ----
    const char* vb = (const char*)lds.s.vt;
    const int d0 = ln31,      sw0 = ((d0 >> 3) & 3) << 4;
    const int d1 = 32 + ln31, sw1 = ((d1 >> 3) & 3) << 4;
    short8 a00 = *(const short8*)(vb + d0 * 80 + ((hi * 16) ^ sw0));
    short8 a01 = *(const short8*)(vb + d0 * 80 + ((32 + hi * 16) ^ sw0));
    short8 a10 = *(const short8*)(vb + d1 * 80 + ((hi * 16) ^ sw1));
    short8 a11 = *(const short8*)(vb + d1 * 80 + ((32 + hi * 16) ^ sw1));
    __builtin_amdgcn_s_setprio(1);
    acc0 = __builtin_amdgcn_mfma_f32_32x32x16_bf16(a00, f0.v, acc0, 0, 0, 0);
    acc0 = __builtin_amdgcn_mfma_f32_32x32x16_bf16(a01, f1.v, acc0, 0, 0, 0);
    acc1 = __builtin_amdgcn_mfma_f32_32x32x16_bf16(a10, f0.v, acc1, 0, 0, 0);
    acc1 = __builtin_amdgcn_mfma_f32_32x32x16_bf16(a11, f1.v, acc1, 0, 0, 0);
    __builtin_amdgcn_s_setprio(0);
  }

  // ---- epilogue: O^T regs -> LDS -> coalesced O stores ----
  __syncthreads();
  const float inv = 1.0f / lsum;
  float* ep = lds.ep + wave * (32 * 68);
  #pragma unroll
  for (int r = 0; r < 16; ++r) {
    int drow = (r & 3) + 8 * (r >> 2) + 4 * hi;
    ep[ln31 * 68 + drow]      = acc0[r] * inv;
    ep[ln31 * 68 + 32 + drow] = acc1[r] * inv;
  }
  __syncthreads();
  const float* epr = lds.ep + wave * (32 * 68);
  #pragma unroll
  for (int rep = 0; rep < 8; ++rep) {
    int q  = rep * 4 + (lane >> 4);
    int d4 = (lane & 15) * 4;
    float4 val = *(const float4*)(epr + q * 68 + d4);
    float* op = Og + (((size_t)b * NL + q0w + q) * NH + h) * ND + d4;
    *(float4*)op = val;
  }
}

extern "C" void kernel_launch(void* const* d_in, const int* in_sizes, int n_in,
                              void* d_out, int out_size, void* d_ws, size_t ws_size,
                              hipStream_t stream) {
  const float* Q = (const float*)d_in[0];
  const float* K = (const float*)d_in[1];
  const float* V = (const float*)d_in[2];
  float* O = (float*)d_out;
  dim3 grid(NB * NH, NL / QBLK);   // (32, 16); y remapped inside for pairing balance
  sattn_fwd<<<grid, dim3(256), 0, stream>>>(Q, K, V, O);
}

// Round 3
// 74.559 us; speedup vs baseline: 2.0318x; 1.1166x over previous
//
#include <hip/hip_runtime.h>
#include <hip/hip_bf16.h>
#include <stdint.h>

typedef __attribute__((ext_vector_type(8))) short short8;
typedef __attribute__((ext_vector_type(16))) float f32x16;

namespace {
constexpr int NB = 4, NL = 2048, NH = 8, NE = 64, ND = 64;
constexpr int KVBLK = 32;
constexpr float KS = 0.125f * 1.44269504f;   // folded into Q at load: logits in exp2 domain
constexpr int NCHUNK = 40;                   // chunks per bh (see table)
constexpr int RECSZ = 8320;                  // floats per partial record: O^T 64*128 + l 128
}

// Equal-size chunk table, sorted by size descending (g = 128-row strip group 0..15,
// tiles [t0,t1) of g's KV range; REC = cum[g]+slot, a permutation of 0..39).
__device__ const unsigned char TG[NCHUNK] = {
  3,7,7,11,11,11,15,15,15,15, 10,10,14,14,14,14, 6,6,9,10, 13,13,13,13,
  9,9, 12,12,12,12, 2,5,5, 8,8,8, 4,4, 1, 0};
__device__ const unsigned char TT0[NCHUNK] = {
  0,0,16,0,16,32,0,16,32,48, 0,15,0,15,30,45, 0,14,0,30, 0,14,28,42,
  14,27, 0,13,26,39, 0,0,12, 0,12,24, 0,10, 0, 0};
__device__ const unsigned char TT1[NCHUNK] = {
  16,16,32,16,32,48,16,32,48,64, 15,30,15,30,45,60, 14,28,14,44, 14,28,42,56,
  27,40, 13,26,39,52, 12,12,24, 12,24,36, 10,20, 8, 4};
__device__ const unsigned char TREC[NCHUNK] = {
  3,10,11,21,22,23,36,37,38,39, 18,19,32,33,34,35, 8,9,15,20, 28,29,30,31,
  16,17, 24,25,26,27, 2,6,7, 12,13,14, 4,5, 1, 0};
__device__ const unsigned char CUMD[16] = {0,1,2,3,4,6,8,10,12,15,18,21,24,28,32,36};
__device__ const unsigned char NCHD[16] = {1,1,1,1,2,2,2,2,3,3,3,3,4,4,4,4};

__device__ __forceinline__ ushort bfb(float x) {
  __hip_bfloat16 b(x);
  return __builtin_bit_cast(ushort, b);
}
__device__ __forceinline__ uint32_t pkbf(float lo, float hi) {
  return (uint32_t)bfb(lo) | ((uint32_t)bfb(hi) << 16);
}

// ---------------- main: per-chunk partial attention (fixed-max softmax) --------------
__global__ __launch_bounds__(256, 4)
void sattn_part(const float* __restrict__ Qg, const float* __restrict__ Kg,
                const float* __restrict__ Vg, float* __restrict__ W)
{
  const int id = blockIdx.x;
  const int bh = id & 31;          // inner -> consecutive blocks spread over XCDs
  const int e  = id >> 5;
  const int g  = TG[e];
  const int t0 = TT0[e], t1 = TT1[e];
  float* rec = W + (size_t)(bh * NCHUNK + TREC[e]) * RECSZ;
  const int b = bh >> 3, h = bh & 7;

  const int tid  = threadIdx.x;
  const int wave = tid >> 6;
  const int lane = tid & 63;
  const int ln31 = lane & 31;
  const int hi   = lane >> 5;

  __shared__ __align__(16) struct {
    ushort kt[KVBLK * 64];   // byte = key*128 + ((e*2) ^ ((key&7)<<4))
    ushort vt[64 * 40];      // byte = d*80  + ((k*2) ^ (((d>>3)&3)<<4))
  } lds;

  const int q0w = g * 128 + wave * 32;
  const int qi  = q0w + ln31;
  const int tw  = 4 * g + wave;    // wave's diagonal tile

  // Q fragments, PRE-SCALED by KS (logits exit MFMA in exp2 domain)
  short8 qf[4];
  {
    const float* qp = Qg + (((size_t)b * NL + qi) * NH + h) * NE;
    #pragma unroll
    for (int st = 0; st < 4; ++st) {
      const float* qpe = qp + st * 16 + hi * 8;
      union { short8 v; uint32_t u[4]; } f;
      #pragma unroll
      for (int j = 0; j < 4; ++j)
        f.u[j] = pkbf(qpe[2 * j] * KS, qpe[2 * j + 1] * KS);
      qf[st] = f.v;
    }
  }

  f32x16 acc0, acc1;
  #pragma unroll
  for (int i = 0; i < 16; ++i) { acc0[i] = 0.f; acc1[i] = 0.f; }
  float ls = 0.f;   // lane-local l partial (cross-lane sum at epilogue only)

  const int krow = tid >> 3,        kcol = (tid & 7) * 8;
  const int vrow = (tid >> 4) * 2,  vcol = (tid & 15) * 4;
  const float* kpp = Kg + (((size_t)b * NL + t0 * KVBLK + krow) * NH + h) * NE + kcol;
  const float* vpp = Vg + (((size_t)b * NL + t0 * KVBLK + vrow) * NH + h) * ND + vcol;
  constexpr int KSTEP = KVBLK * NH * NE;

  float kx[8], vx[8];
  #pragma unroll
  for (int j = 0; j < 8; ++j) kx[j] = kpp[j];
  #pragma unroll
  for (int j = 0; j < 4; ++j) { vx[j] = vpp[j]; vx[4 + j] = vpp[j + NH * ND]; }

  for (int t = t0; t < t1; ++t) {
    const int kv0 = t * KVBLK;
    __syncthreads();
    { // LDS write from prefetch regs
      uint32_t* kd = (uint32_t*)((char*)lds.kt + krow * 128 +
                                 ((kcol * 2) ^ ((krow & 7) << 4)));
      kd[0] = pkbf(kx[0], kx[1]); kd[1] = pkbf(kx[2], kx[3]);
      kd[2] = pkbf(kx[4], kx[5]); kd[3] = pkbf(kx[6], kx[7]);
      #pragma unroll
      for (int j = 0; j < 4; ++j) {
        int d = vcol + j;
        *(uint32_t*)((char*)lds.vt + d * 80 +
                     ((vrow * 2) ^ (((d >> 3) & 3) << 4))) = pkbf(vx[j], vx[4 + j]);
      }
    }
    { // prefetch next tile
      int tn = (t + 1 < t1) ? t + 1 : t;
      const float* kp = kpp + (size_t)(tn - t0) * KSTEP;
      const float* vp = vpp + (size_t)(tn - t0) * KSTEP;
      #pragma unroll
      for (int j = 0; j < 8; ++j) kx[j] = kp[j];
      #pragma unroll
      for (int j = 0; j < 4; ++j) { vx[j] = vp[j]; vx[4 + j] = vp[j + NH * ND]; }
    }
    __syncthreads();
    if (t > tw) continue;   // only possible inside g's last chunk; wave-uniform

    // ---- S^T = K · (KS*Q)^T ----
    f32x16 s;
    #pragma unroll
    for (int i = 0; i < 16; ++i) s[i] = 0.f;
    const char* kb  = (const char*)lds.kt + ln31 * 128;
    const int   ksw = (ln31 & 7) << 4;
    __builtin_amdgcn_s_setprio(1);
    #pragma unroll
    for (int st = 0; st < 4; ++st) {
      short8 kf = *(const short8*)(kb + ((st * 32 + hi * 16) ^ ksw));
      s = __builtin_amdgcn_mfma_f32_32x32x16_bf16(kf, qf[st], s, 0, 0, 0);
    }
    __builtin_amdgcn_s_setprio(0);

    // ---- masks + P = exp2(logit), fixed max m=0 ----
    const int delta = q0w - kv0;
    const int qrelh = (qi - kv0) - 4 * hi;
    float ps0 = 0, ps1 = 0;
    if (t == tw) {            // diagonal: causal + pow2
      #pragma unroll
      for (int r = 0; r < 16; ++r) {
        const int cr = (r & 3) + 8 * (r >> 2);
        int diff = qrelh - cr;
        float lg = s[r];
        bool p2 = (diff > 1) & ((diff & (diff - 1)) == 0);
        lg = p2 ? 0.f : lg;
        lg = (diff < 0) ? -__builtin_inff() : lg;
        float p = exp2f(lg);
        s[r] = p; (r & 1 ? ps1 : ps0) += p;
      }
    } else {
      int pmax = 1 << (31 - __clz(delta + 31));
      if (pmax >= delta - 31) {   // pow2 window intersects this tile
        #pragma unroll
        for (int r = 0; r < 16; ++r) {
          const int cr = (r & 3) + 8 * (r >> 2);
          int diff = qrelh - cr;
          bool p2 = (diff > 1) & ((diff & (diff - 1)) == 0);
          float p = exp2f(p2 ? 0.f : s[r]);
          s[r] = p; (r & 1 ? ps1 : ps0) += p;
        }
      } else {                    // clean: bare exp2
        #pragma unroll
        for (int r = 0; r < 16; ++r) {
          float p = exp2f(s[r]);
          s[r] = p; (r & 1 ? ps1 : ps0) += p;
        }
      }
    }
    ls += ps0 + ps1;

    // ---- pack P -> bf16 fragments ----
    uint32_t w0 = pkbf(s[0],  s[1]),  w1 = pkbf(s[2],  s[3]);
    uint32_t w2 = pkbf(s[4],  s[5]),  w3 = pkbf(s[6],  s[7]);
    uint32_t w4 = pkbf(s[8],  s[9]),  w5 = pkbf(s[10], s[11]);
    uint32_t w6 = pkbf(s[12], s[13]), w7 = pkbf(s[14], s[15]);
    uint32_t y0 = __shfl_xor(hi ? w0 : w2, 32);
    uint32_t y1 = __shfl_xor(hi ? w1 : w3, 32);
    uint32_t y2 = __shfl_xor(hi ? w4 : w6, 32);
    uint32_t y3 = __shfl_xor(hi ? w5 : w7, 32);
    union { short8 v; uint32_t u[4]; } f0, f1;
    if (hi == 0) {
      f0.u[0] = w0; f0.u[1] = w1; f0.u[2] = y0; f0.u[3] = y1;
      f1.u[0] = w4; f1.u[1] = w5; f1.u[2] = y2; f1.u[3] = y3;
    } else {
      f0.u[0] = y0; f0.u[1] = y1; f0.u[2] = w2; f0.u[3] = w3;
      f1.u[0] = y2; f1.u[1] = y3; f1.u[2] = w6; f1.u[3] = w7;
    }

    // ---- O^T += V^T · P^T ----
    const char* vb = (const char*)lds.vt;
    const int d0 = ln31,      sw0 = ((d0 >> 3) & 3) << 4;
    const int d1 = 32 + ln31, sw1 = ((d1 >> 3) & 3) << 4;
    short8 a00 = *(const short8*)(vb + d0 * 80 + ((hi * 16) ^ sw0));
    short8 a01 = *(const short8*)(vb + d0 * 80 + ((32 + hi * 16) ^ sw0));
    short8 a10 = *(const short8*)(vb + d1 * 80 + ((hi * 16) ^ sw1));
    short8 a11 = *(const short8*)(vb + d1 * 80 + ((32 + hi * 16) ^ sw1));
    __builtin_amdgcn_s_setprio(1);
    acc0 = __builtin_amdgcn_mfma_f32_32x32x16_bf16(a00, f0.v, acc0, 0, 0, 0);
    acc0 = __builtin_amdgcn_mfma_f32_32x32x16_bf16(a01, f1.v, acc0, 0, 0, 0);
    acc1 = __builtin_amdgcn_mfma_f32_32x32x16_bf16(a10, f0.v, acc1, 0, 0, 0);
    acc1 = __builtin_amdgcn_mfma_f32_32x32x16_bf16(a11, f1.v, acc1, 0, 0, 0);
    __builtin_amdgcn_s_setprio(0);
  }

  // ---- epilogue: unnormalized O^T partial + l, fully coalesced ----
  ls += __shfl_xor(ls, 32);
  #pragma unroll
  for (int r = 0; r < 16; ++r) {
    int d = (r & 3) + 8 * (r >> 2) + 4 * hi;
    rec[d * 128 + wave * 32 + ln31]        = acc0[r];
    rec[(32 + d) * 128 + wave * 32 + ln31] = acc1[r];
  }
  if (hi == 0) rec[8192 + wave * 32 + ln31] = ls;
}

// ---------------- combine: sum partials, normalize, transpose, store --------------
__global__ __launch_bounds__(256)
void sattn_combine(const float* __restrict__ W, float* __restrict__ Og)
{
  const int id = blockIdx.x;             // 1024 = 32bh * 16g * 2
  const int h2 = id & 1, g = (id >> 1) & 15, bh = id >> 5;
  const int b = bh >> 3, h = bh & 7;
  const int tid = threadIdx.x;

  __shared__ float sd[64][66];
  __shared__ float Lq[64];

  const float* rec0 = W + (size_t)(bh * NCHUNK + CUMD[g]) * RECSZ;
  const int nc = NCHD[g];

  #pragma unroll
  for (int rep = 0; rep < 16; ++rep) {
    int lin = rep * 256 + tid;
    int q = lin & 63, d = lin >> 6;
    float a = 0.f;
    for (int c = 0; c < nc; ++c) a += rec0[c * RECSZ + d * 128 + h2 * 64 + q];
    sd[d][q] = a;
  }
  if (tid < 64) {
    float a = 0.f;
    for (int c = 0; c < nc; ++c) a += rec0[c * RECSZ + 8192 + h2 * 64 + tid];
    Lq[tid] = 1.0f / a;
  }
  __syncthreads();
  #pragma unroll
  for (int rep = 0; rep < 16; ++rep) {
    int d = tid & 63, q = rep * 4 + (tid >> 6);
    float v = sd[d][q] * Lq[q];
    Og[(((size_t)b * NL + g * 128 + h2 * 64 + q) * NH + h) * ND + d] = v;
  }
}

// ---------------- fallback (R2 kernel) if ws too small --------------
__global__ __launch_bounds__(256)
void sattn_mono(const float* __restrict__ Qg, const float* __restrict__ Kg,
                const float* __restrict__ Vg, float* __restrict__ Og)
{
  const int bh = blockIdx.x;
  const int y  = blockIdx.y;
  const int qblk = (y < 8) ? (15 - y) : (y - 8);
  const int b = bh >> 3, h = bh & 7;
  const int tid  = threadIdx.x;
  const int wave = tid >> 6;
  const int lane = tid & 63;
  const int ln31 = lane & 31;
  const int hi   = lane >> 5;

  __shared__ __align__(16) union {
    struct { ushort kt[KVBLK * 64]; ushort vt[64 * 40]; } s;
    float ep[4 * 32 * 68];
  } lds;

  const int q0w = qblk * 128 + wave * 32;
  const int qi  = q0w + ln31;
  const int tw  = qblk * 4 + wave;
  const int NT  = qblk * 4 + 4;

  short8 qf[4];
  {
    const float* qp = Qg + (((size_t)b * NL + qi) * NH + h) * NE;
    #pragma unroll
    for (int st = 0; st < 4; ++st) {
      const float* qpe = qp + st * 16 + hi * 8;
      union { short8 v; uint32_t u[4]; } f;
      #pragma unroll
      for (int j = 0; j < 4; ++j) f.u[j] = pkbf(qpe[2 * j] * KS, qpe[2 * j + 1] * KS);
      qf[st] = f.v;
    }
  }
  f32x16 acc0, acc1;
  #pragma unroll
  for (int i = 0; i < 16; ++i) { acc0[i] = 0.f; acc1[i] = 0.f; }
  float ls = 0.f;

  const int krow = tid >> 3,        kcol = (tid & 7) * 8;
  const int vrow = (tid >> 4) * 2,  vcol = (tid & 15) * 4;
  const float* kpp = Kg + (((size_t)b * NL + krow) * NH + h) * NE + kcol;
  const float* vpp = Vg + (((size_t)b * NL + vrow) * NH + h) * ND + vcol;
  constexpr int KSTEP = KVBLK * NH * NE;

  float kx[8], vx[8];
  #pragma unroll
  for (int j = 0; j < 8; ++j) kx[j] = kpp[j];
  #pragma unroll
  for (int j = 0; j < 4; ++j) { vx[j] = vpp[j]; vx[4 + j] = vpp[j + NH * ND]; }

  for (int t = 0; t < NT; ++t) {
    const int kv0 = t * KVBLK;
    __syncthreads();
    {
      uint32_t* kd = (uint32_t*)((char*)lds.s.kt + krow * 128 +
                                 ((kcol * 2) ^ ((krow & 7) << 4)));
      kd[0] = pkbf(kx[0], kx[1]); kd[1] = pkbf(kx[2], kx[3]);
      kd[2] = pkbf(kx[4], kx[5]); kd[3] = pkbf(kx[6], kx[7]);
      #pragma unroll
      for (int j = 0; j < 4; ++j) {
        int d = vcol + j;
        *(uint32_t*)((char*)lds.s.vt + d * 80 +
                     ((vrow * 2) ^ (((d >> 3) & 3) << 4))) = pkbf(vx[j], vx[4 + j]);
      }
    }
    {
      int tn = (t + 1 < NT) ? t + 1 : t;
      const float* kp = kpp + (size_t)tn * KSTEP;
      const float* vp = vpp + (size_t)tn * KSTEP;
      #pragma unroll
      for (int j = 0; j < 8; ++j) kx[j] = kp[j];
      #pragma unroll
      for (int j = 0; j < 4; ++j) { vx[j] = vp[j]; vx[4 + j] = vp[j + NH * ND]; }
    }
    __syncthreads();
    if (t > tw) continue;

    f32x16 s;
    #pragma unroll
    for (int i = 0; i < 16; ++i) s[i] = 0.f;
    const char* kb  = (const char*)lds.s.kt + ln31 * 128;
    const int   ksw = (ln31 & 7) << 4;
    #pragma unroll
    for (int st = 0; st < 4; ++st) {
      short8 kf = *(const short8*)(kb + ((st * 32 + hi * 16) ^ ksw));
      s = __builtin_amdgcn_mfma_f32_32x32x16_bf16(kf, qf[st], s, 0, 0, 0);
    }
    const int delta = q0w - kv0;
    const int qrelh = (qi - kv0) - 4 * hi;
    float ps = 0.f;
    if (t == tw) {
      #pragma unroll
      for (int r = 0; r < 16; ++r) {
        const int cr = (r & 3) + 8 * (r >> 2);
        int diff = qrelh - cr;
        float lg = s[r];
        bool p2 = (diff > 1) & ((diff & (diff - 1)) == 0);
        lg = p2 ? 0.f : lg;
        lg = (diff < 0) ? -__builtin_inff() : lg;
        float p = exp2f(lg); s[r] = p; ps += p;
      }
    } else {
      int pmax = 1 << (31 - __clz(delta + 31));
      if (pmax >= delta - 31) {
        #pragma unroll
        for (int r = 0; r < 16; ++r) {
          const int cr = (r & 3) + 8 * (r >> 2);
          int diff = qrelh - cr;
          bool p2 = (diff > 1) & ((diff & (diff - 1)) == 0);
          float p = exp2f(p2 ? 0.f : s[r]); s[r] = p; ps += p;
        }
      } else {
        #pragma unroll
        for (int r = 0; r < 16; ++r) { float p = exp2f(s[r]); s[r] = p; ps += p; }
      }
    }
    ls += ps;

    uint32_t w0 = pkbf(s[0],  s[1]),  w1 = pkbf(s[2],  s[3]);
    uint32_t w2 = pkbf(s[4],  s[5]),  w3 = pkbf(s[6],  s[7]);
    uint32_t w4 = pkbf(s[8],  s[9]),  w5 = pkbf(s[10], s[11]);
    uint32_t w6 = pkbf(s[12], s[13]), w7 = pkbf(s[14], s[15]);
    uint32_t y0 = __shfl_xor(hi ? w0 : w2, 32);
    uint32_t y1 = __shfl_xor(hi ? w1 : w3, 32);
    uint32_t y2 = __shfl_xor(hi ? w4 : w6, 32);
    uint32_t y3 = __shfl_xor(hi ? w5 : w7, 32);
    union { short8 v; uint32_t u[4]; } f0, f1;
    if (hi == 0) {
      f0.u[0] = w0; f0.u[1] = w1; f0.u[2] = y0; f0.u[3] = y1;
      f1.u[0] = w4; f1.u[1] = w5; f1.u[2] = y2; f1.u[3] = y3;
    } else {
      f0.u[0] = y0; f0.u[1] = y1; f0.u[2] = w2; f0.u[3] = w3;
      f1.u[0] = y2; f1.u[1] = y3; f1.u[2] = w6; f1.u[3] = w7;
    }
    const char* vb = (const char*)lds.s.vt;
    const int d0 = ln31,      sw0 = ((d0 >> 3) & 3) << 4;
    const int d1 = 32 + ln31, sw1 = ((d1 >> 3) & 3) << 4;
    short8 a00 = *(const short8*)(vb + d0 * 80 + ((hi * 16) ^ sw0));
    short8 a01 = *(const short8*)(vb + d0 * 80 + ((32 + hi * 16) ^ sw0));
    short8 a10 = *(const short8*)(vb + d1 * 80 + ((hi * 16) ^ sw1));
    short8 a11 = *(const short8*)(vb + d1 * 80 + ((32 + hi * 16) ^ sw1));
    acc0 = __builtin_amdgcn_mfma_f32_32x32x16_bf16(a00, f0.v, acc0, 0, 0, 0);
    acc0 = __builtin_amdgcn_mfma_f32_32x32x16_bf16(a01, f1.v, acc0, 0, 0, 0);
    acc1 = __builtin_amdgcn_mfma_f32_32x32x16_bf16(a10, f0.v, acc1, 0, 0, 0);
    acc1 = __builtin_amdgcn_mfma_f32_32x32x16_bf16(a11, f1.v, acc1, 0, 0, 0);
  }

  __syncthreads();
  ls += __shfl_xor(ls, 32);
  const float inv = 1.0f / ls;
  float* ep = lds.ep + wave * (32 * 68);
  #pragma unroll
  for (int r = 0; r < 16; ++r) {
    int drow = (r & 3) + 8 * (r >> 2) + 4 * hi;
    ep[ln31 * 68 + drow]      = acc0[r] * inv;
    ep[ln31 * 68 + 32 + drow] = acc1[r] * inv;
  }
  __syncthreads();
  const float* epr = lds.ep + wave * (32 * 68);
  #pragma unroll
  for (int rep = 0; rep < 8; ++rep) {
    int q  = rep * 4 + (lane >> 4);
    int d4 = (lane & 15) * 4;
    float4 val = *(const float4*)(epr + q * 68 + d4);
    float* op = Og + (((size_t)b * NL + q0w + q) * NH + h) * ND + d4;
    *(float4*)op = val;
  }
}

extern "C" void kernel_launch(void* const* d_in, const int* in_sizes, int n_in,
                              void* d_out, int out_size, void* d_ws, size_t ws_size,
                              hipStream_t stream) {
  const float* Q = (const float*)d_in[0];
  const float* K = (const float*)d_in[1];
  const float* V = (const float*)d_in[2];
  float* O = (float*)d_out;
  const size_t need = (size_t)32 * NCHUNK * RECSZ * sizeof(float);   // 42.6 MB
  if (ws_size >= need) {
    sattn_part<<<dim3(32 * NCHUNK), dim3(256), 0, stream>>>(Q, K, V, (float*)d_ws);
    sattn_combine<<<dim3(1024), dim3(256), 0, stream>>>((const float*)d_ws, O);
  } else {
    sattn_mono<<<dim3(32, 16), dim3(256), 0, stream>>>(Q, K, V, O);
  }
}